// Round 3
// baseline (245.578 us; speedup 1.0000x reference)
//
#include <hip/hip_runtime.h>
#include <hip/hip_cooperative_groups.h>

namespace cg = cooperative_groups;

// Per-class k-th order statistic (quantile) for Logit_Linear.get_th,
// fully fused into ONE cooperative kernel (4 phases, 3 grid syncs):
//  1) per-block LDS-privatized per-class 8-bit histogram (+ block max)
//  2) per-class reduce -> count, k, coarse bucket   (block c handles class c)
//  3) gather candidates of each class's bucket into compact per-class lists
//  4) per-class 3x8-bit radix select over staged candidates

#define MAXC      128        // supports class_num <= 128 (problem: 100)
#define NB        128        // blocks (<= 256 CUs, co-resident for coop launch)
#define NT        1024       // threads per block
#define NCHUNK    8
#define BPC       (NB / NCHUNK)
#define STAGE_CAP 12288      // candidates staged in LDS in phase 4 (48 KB)
#define CAND_CAP  (1u << 21) // candidate buffer words (covers n <= 2M)

__device__ unsigned int g_partial[NB * MAXC * 128]; // packed u16 digit pairs
__device__ unsigned int g_blockmax[NB];
__device__ unsigned int g_bucket[MAXC];
__device__ int          g_rem[MAXC];
__device__ unsigned int g_bcount[MAXC];
__device__ unsigned int g_usemax[MAXC];
__device__ unsigned int g_ccursor[MAXC];
__device__ unsigned int g_cbase[MAXC];
__device__ unsigned int g_cand[CAND_CAP];

__device__ __forceinline__ unsigned int fkey(float f) {
    unsigned int u = __float_as_uint(f);
    return (u & 0x80000000u) ? ~u : (u | 0x80000000u);
}
__device__ __forceinline__ float ikey(unsigned int u) {
    unsigned int b = (u & 0x80000000u) ? (u ^ 0x80000000u) : ~u;
    return __uint_as_float(b);
}

__global__ __launch_bounds__(NT) void fused_kernel(const float* __restrict__ score,
                                                   const int* __restrict__ label,
                                                   int n,
                                                   const int* __restrict__ cnp,
                                                   const int* __restrict__ epsp,
                                                   float* __restrict__ out) {
    cg::grid_group grid = cg::this_grid();
    __shared__ unsigned int smem[MAXC * 128];   // 64 KiB, re-carved per phase
    __shared__ unsigned int saux[32];
    const int t = threadIdx.x;
    const int b = blockIdx.x;
    int cn = *cnp; if (cn > MAXC) cn = MAXC;

    // ------------------------------------------------------------ phase 1 --
    for (int i = t; i < MAXC * 128; i += NT) smem[i] = 0u;
    __syncthreads();

    const int per = ((n + NB - 1) / NB + 3) & ~3;
    const int i0 = b * per;
    const int i1 = min(n, i0 + per);
    const int nv = (i1 > i0) ? ((i1 - i0) >> 2) : 0;
    const float4* s4 = (const float4*)(score + i0);
    const int4*   l4 = (const int4*)(label + i0);
    unsigned int lmax = 0u;

    for (int j = t; j < nv; j += NT) {
        float4 s = s4[j]; int4 l = l4[j];
        float sv[4] = {s.x, s.y, s.z, s.w};
        int   lv[4] = {l.x, l.y, l.z, l.w};
#pragma unroll
        for (int q = 0; q < 4; ++q) {
            unsigned int u = fkey(sv[q]);
            int c = lv[q] & (MAXC - 1);
            lmax = lmax > u ? lmax : u;
            atomicAdd(&smem[(c << 7) | (u >> 25)], ((u >> 24) & 1u) ? 65536u : 1u);
        }
    }
    for (int i = i0 + (nv << 2) + t; i < i1; i += NT) {
        unsigned int u = fkey(score[i]);
        int c = label[i] & (MAXC - 1);
        lmax = lmax > u ? lmax : u;
        atomicAdd(&smem[(c << 7) | (u >> 25)], ((u >> 24) & 1u) ? 65536u : 1u);
    }
#pragma unroll
    for (int off = 32; off; off >>= 1) {
        unsigned int o = (unsigned int)__shfl_xor((int)lmax, off, 64);
        lmax = lmax > o ? lmax : o;
    }
    if ((t & 63) == 0) saux[t >> 6] = lmax;
    __syncthreads();
    if (t == 0) {
        unsigned int m = saux[0];
        for (int w = 1; w < NT / 64; ++w) m = m > saux[w] ? m : saux[w];
        g_blockmax[b] = m;
    }
    {   // non-atomic flush of this block's partial histogram
        unsigned int* dst = &g_partial[b * (MAXC * 128)];
        for (int i = t; i < (cn << 7); i += NT) dst[i] = smem[i];
    }
    __threadfence();
    grid.sync();

    // ------------------------------------------------------------ phase 2 --
    {
        unsigned int* RED  = smem;          // 8 x 256
        unsigned int* HIST = smem + 2048;   // 256
        unsigned int* SCAN = smem + 2304;   // 256
        for (int c = b; c < cn; c += NB) {
            const int pair = t & 127, chunk = t >> 7;
            unsigned int lo = 0u, hi = 0u;
            const unsigned int* p = &g_partial[(c << 7) + pair];
            for (int j = 0; j < BPC; ++j) {
                unsigned int w = p[(chunk * BPC + j) * (MAXC * 128)];
                lo += w & 0xFFFFu; hi += w >> 16;
            }
            RED[chunk * 256 + 2 * pair]     = lo;
            RED[chunk * 256 + 2 * pair + 1] = hi;
            __syncthreads();
            if (t < 256) {
                unsigned int s = 0u;
                for (int k2 = 0; k2 < NCHUNK; ++k2) s += RED[k2 * 256 + t];
                HIST[t] = s; SCAN[t] = s;
            }
            __syncthreads();
            for (int off = 1; off < 256; off <<= 1) {
                unsigned int add = (t < 256 && t >= off) ? SCAN[t - off] : 0u;
                __syncthreads();
                if (t < 256) SCAN[t] += add;
                __syncthreads();
            }
            unsigned int count = SCAN[255];
            // replicate JAX/NumPy weak-typed f32 arithmetic (verified exact)
            double eps = (double)(*epsp) / 100.0;
            float fac = (float)(1.0 - eps);
            int k = (int)((float)count * fac);
            int usemax = (count == 0u) || (k >= (int)count);
            if (t == 0) {
                g_usemax[c] = (unsigned)usemax;
                g_ccursor[c] = 0u;
                if (usemax) g_bcount[c] = 0u;
            }
            if (!usemax && t < 256) {
                unsigned int incl = SCAN[t], excl = incl - HIST[t];
                if ((unsigned)k >= excl && (unsigned)k < incl) {
                    g_bucket[c] = (unsigned)t;
                    g_rem[c]    = k - (int)excl;
                    g_bcount[c] = HIST[t];
                }
            }
            __syncthreads();
        }
    }
    __threadfence();
    grid.sync();

    // ------------------------------------------------------------ phase 3 --
    {
        unsigned int* sbucket = smem;             // MAXC
        unsigned int* scnt    = smem + MAXC;      // MAXC
        unsigned int* sbase   = smem + 2 * MAXC;  // MAXC
        unsigned int* scbase  = smem + 3 * MAXC;  // MAXC
        unsigned int* stmp    = smem + 4 * MAXC;  // MAXC
        unsigned int mybc = 0u;
        if (t < MAXC) {
            int live = (t < cn) && !g_usemax[t];
            mybc = live ? g_bcount[t] : 0u;
            sbucket[t] = live ? g_bucket[t] : 0xFFFFFFFFu;
            scnt[t] = 0u;
            stmp[t] = mybc;
        }
        __syncthreads();
        for (int off = 1; off < MAXC; off <<= 1) {
            unsigned int add = (t < MAXC && t >= off) ? stmp[t - off] : 0u;
            __syncthreads();
            if (t < MAXC) stmp[t] += add;
            __syncthreads();
        }
        if (t < MAXC) {
            scbase[t] = stmp[t] - mybc;           // exclusive class base
            if (b == 0) g_cbase[t] = scbase[t];
        }
        __syncthreads();

        // pass A: count bucket members per class in this block's slice
        for (int j = t; j < nv; j += NT) {
            float4 s = s4[j]; int4 l = l4[j];
            float sv[4] = {s.x, s.y, s.z, s.w};
            int   lv[4] = {l.x, l.y, l.z, l.w};
#pragma unroll
            for (int q = 0; q < 4; ++q) {
                unsigned int u = fkey(sv[q]);
                int c = lv[q] & (MAXC - 1);
                if ((u >> 24) == sbucket[c]) atomicAdd(&scnt[c], 1u);
            }
        }
        for (int i = i0 + (nv << 2) + t; i < i1; i += NT) {
            unsigned int u = fkey(score[i]);
            int c = label[i] & (MAXC - 1);
            if ((u >> 24) == sbucket[c]) atomicAdd(&scnt[c], 1u);
        }
        __syncthreads();
        if (t < MAXC) {
            unsigned int cnt = scnt[t];
            sbase[t] = cnt ? atomicAdd(&g_ccursor[t], cnt) : 0u;
            scnt[t] = 0u;  // reuse as local write cursor
        }
        __syncthreads();
        // pass B: write candidates (slice is L1/L2-hot from pass A)
        for (int j = t; j < nv; j += NT) {
            float4 s = s4[j]; int4 l = l4[j];
            float sv[4] = {s.x, s.y, s.z, s.w};
            int   lv[4] = {l.x, l.y, l.z, l.w};
#pragma unroll
            for (int q = 0; q < 4; ++q) {
                unsigned int u = fkey(sv[q]);
                int c = lv[q] & (MAXC - 1);
                if ((u >> 24) == sbucket[c]) {
                    unsigned int pos = atomicAdd(&scnt[c], 1u);
                    g_cand[scbase[c] + sbase[c] + pos] = u;
                }
            }
        }
        for (int i = i0 + (nv << 2) + t; i < i1; i += NT) {
            unsigned int u = fkey(score[i]);
            int c = label[i] & (MAXC - 1);
            if ((u >> 24) == sbucket[c]) {
                unsigned int pos = atomicAdd(&scnt[c], 1u);
                g_cand[scbase[c] + sbase[c] + pos] = u;
            }
        }
    }
    __threadfence();
    grid.sync();

    // ------------------------------------------------------------ phase 4 --
    {
        unsigned int* scand = smem;                    // STAGE_CAP
        unsigned int* sh    = smem + STAGE_CAP;        // 256
        unsigned int* ss    = smem + STAGE_CAP + 256;  // 256
        for (int c = b; c < cn; c += NB) {
            if (g_usemax[c]) {  // empty class / k>=count: global max score
                if (t < NB) sh[t] = g_blockmax[t];
                __syncthreads();
                for (int off = NB / 2; off; off >>= 1) {
                    if (t < off) { unsigned int a = sh[t + off]; if (a > sh[t]) sh[t] = a; }
                    __syncthreads();
                }
                if (t == 0) out[c] = ikey(sh[0]);
                __syncthreads();
                continue;
            }
            const unsigned int base = g_cbase[c];
            const unsigned int m = g_bcount[c];
            int rem = g_rem[c];
            unsigned int pref = g_bucket[c] << 24;
            const unsigned int* src;
            if (m <= STAGE_CAP) {
                for (unsigned int j = t; j < m; j += NT) scand[j] = g_cand[base + j];
                __syncthreads();
                src = scand;
            } else {
                src = &g_cand[base];
                __syncthreads();
            }
            for (int shift = 16; shift >= 0; shift -= 8) {
                if (t < 256) sh[t] = 0u;
                __syncthreads();
                for (unsigned int j = t; j < m; j += NT) {
                    unsigned int u = src[j];
                    if ((u >> (shift + 8)) == (pref >> (shift + 8)))
                        atomicAdd(&sh[(u >> shift) & 255u], 1u);
                }
                __syncthreads();
                if (t < 256) ss[t] = sh[t];
                __syncthreads();
                for (int off = 1; off < 256; off <<= 1) {
                    unsigned int add = (t < 256 && t >= off) ? ss[t - off] : 0u;
                    __syncthreads();
                    if (t < 256) ss[t] += add;
                    __syncthreads();
                }
                if (t < 256) {
                    unsigned int incl = ss[t], excl = incl - sh[t];
                    if ((unsigned)rem >= excl && (unsigned)rem < incl) {
                        saux[16] = (unsigned)t; saux[17] = excl;
                    }
                }
                __syncthreads();
                rem -= (int)saux[17];
                pref |= saux[16] << shift;
                __syncthreads();
            }
            if (t == 0) out[c] = ikey(pref);
            __syncthreads();
        }
    }
}

extern "C" void kernel_launch(void* const* d_in, const int* in_sizes, int n_in,
                              void* d_out, int out_size, void* d_ws, size_t ws_size,
                              hipStream_t stream) {
    const float* score = (const float*)d_in[0];
    const int*   label = (const int*)d_in[1];
    const int*   cnp   = (const int*)d_in[2];
    const int*   epsp  = (const int*)d_in[3];
    float*       out   = (float*)d_out;
    int n = in_sizes[0];

    void* args[] = {(void*)&score, (void*)&label, (void*)&n,
                    (void*)&cnp, (void*)&epsp, (void*)&out};
    hipLaunchCooperativeKernel((const void*)fused_kernel, dim3(NB), dim3(NT),
                               args, 0, stream);
}

// Round 4
// 232.797 us; speedup vs baseline: 1.0549x; 1.0549x over previous
//
#include <hip/hip_runtime.h>

// Per-class k-th order statistic (quantile) for Logit_Linear.get_th.
// K1: per-block LDS-privatized per-class 8-bit histogram of fkey(score).
// K2 (256 blocks == #CUs, all co-resident; flag-based ordering):
//   A) blocks 0..cn-1: reduce partials for class b -> count, k, bucket
//   B) all blocks: gather candidates of each class's bucket (compact lists)
//   C) blocks 0..cn-1: 3x8-bit radix select over candidates -> out[c]

#define MAXC      128        // supports class_num <= 128 (problem: 100)
#define NB1       128        // K1 blocks
#define T1        1024       // K1 threads
#define NB2       256        // K2 blocks (== CU count -> co-resident)
#define T2        512        // K2 threads
#define BPC       (NB1 / 4)  // scan-blocks per chunk in stage A
#define STAGE_CAP 8192       // candidates staged in LDS in stage C (32 KB)
#define CAND_CAP  (1u << 21) // candidate buffer words (covers n <= 2M)

__device__ unsigned int g_partial[NB1 * MAXC * 128]; // packed u16 digit pairs
__device__ unsigned int g_blockmax[NB1];
__device__ unsigned int g_bucket[MAXC];
__device__ int          g_rem[MAXC];
__device__ unsigned int g_bcount[MAXC];
__device__ unsigned int g_usemax[MAXC];
__device__ unsigned int g_ccursor[MAXC];
__device__ unsigned int g_cbase[MAXC];
__device__ unsigned int g_cand[CAND_CAP];
__device__ int          g_readyA;
__device__ int          g_readyB;
__device__ int          g_done;

__device__ __forceinline__ unsigned int fkey(float f) {
    unsigned int u = __float_as_uint(f);
    return (u & 0x80000000u) ? ~u : (u | 0x80000000u);
}
__device__ __forceinline__ float ikey(unsigned int u) {
    unsigned int b = (u & 0x80000000u) ? (u ^ 0x80000000u) : ~u;
    return __uint_as_float(b);
}
__device__ __forceinline__ int aload(int* p) {
    return __hip_atomic_load(p, __ATOMIC_ACQUIRE, __HIP_MEMORY_SCOPE_AGENT);
}
__device__ __forceinline__ void abump(int* p) {
    __hip_atomic_fetch_add(p, 1, __ATOMIC_RELEASE, __HIP_MEMORY_SCOPE_AGENT);
}

// ------------------------------------------------------------------- K1 ----
__global__ __launch_bounds__(T1) void scan_kernel(const float* __restrict__ score,
                                                  const int* __restrict__ label,
                                                  int n, const int* __restrict__ cnp) {
    __shared__ unsigned int lhist[MAXC * 128];
    __shared__ unsigned int wmax[T1 / 64];
    if (blockIdx.x == 0 && threadIdx.x == 0) { g_readyA = 0; g_readyB = 0; g_done = 0; }
    int cn = *cnp; if (cn > MAXC) cn = MAXC;
    for (int i = threadIdx.x; i < MAXC * 128; i += T1) lhist[i] = 0u;
    __syncthreads();

    const int per = ((n + NB1 - 1) / NB1 + 3) & ~3;
    const int i0 = blockIdx.x * per;
    const int i1 = min(n, i0 + per);
    const int nv = (i1 > i0) ? ((i1 - i0) >> 2) : 0;
    const float4* s4 = (const float4*)(score + i0);
    const int4*   l4 = (const int4*)(label + i0);
    unsigned int lmax = 0u;

    for (int j = threadIdx.x; j < nv; j += T1) {
        float4 s = s4[j]; int4 l = l4[j];
        float sv[4] = {s.x, s.y, s.z, s.w};
        int   lv[4] = {l.x, l.y, l.z, l.w};
#pragma unroll
        for (int q = 0; q < 4; ++q) {
            unsigned int u = fkey(sv[q]);
            int c = lv[q] & (MAXC - 1);
            lmax = lmax > u ? lmax : u;
            atomicAdd(&lhist[(c << 7) | (u >> 25)], ((u >> 24) & 1u) ? 65536u : 1u);
        }
    }
    for (int i = i0 + (nv << 2) + threadIdx.x; i < i1; i += T1) {
        unsigned int u = fkey(score[i]);
        int c = label[i] & (MAXC - 1);
        lmax = lmax > u ? lmax : u;
        atomicAdd(&lhist[(c << 7) | (u >> 25)], ((u >> 24) & 1u) ? 65536u : 1u);
    }
#pragma unroll
    for (int off = 32; off; off >>= 1) {
        unsigned int o = (unsigned int)__shfl_xor((int)lmax, off, 64);
        lmax = lmax > o ? lmax : o;
    }
    if ((threadIdx.x & 63) == 0) wmax[threadIdx.x >> 6] = lmax;
    __syncthreads();
    if (threadIdx.x == 0) {
        unsigned int m = wmax[0];
        for (int w = 1; w < T1 / 64; ++w) m = m > wmax[w] ? m : wmax[w];
        g_blockmax[blockIdx.x] = m;
    }
    unsigned int* dst = &g_partial[blockIdx.x * (MAXC * 128)];
    for (int i = threadIdx.x; i < (cn << 7); i += T1) dst[i] = lhist[i];
}

// ------------------------------------------------------------------- K2 ----
__global__ __launch_bounds__(T2) void fuse_kernel(const float* __restrict__ score,
                                                  const int* __restrict__ label,
                                                  int n,
                                                  const int* __restrict__ cnp,
                                                  const int* __restrict__ epsp,
                                                  float* __restrict__ out) {
    __shared__ unsigned int scand[STAGE_CAP];  // 32 KB (stage C)
    __shared__ unsigned int red[4 * 256];      // 4 KB  (stage A)
    __shared__ unsigned int sh[256];
    __shared__ unsigned int ss[256];
    __shared__ unsigned int sb1[MAXC];         // bucket / scan tmp
    __shared__ unsigned int sb2[MAXC];         // per-class count / cursor
    __shared__ unsigned int sb3[MAXC];         // block base within class
    __shared__ unsigned int sb4[MAXC];         // class base
    __shared__ unsigned int sel[2];

    int cn = *cnp; if (cn > MAXC) cn = MAXC;
    const int t = threadIdx.x;
    const int b = blockIdx.x;

    // ------------------------------- stage A: per-class reduce (b < cn) ----
    if (b < cn) {
        const int pair = t & 127, chunk = t >> 7;  // 4 chunks x BPC blocks
        unsigned int lo = 0u, hi = 0u;
        const unsigned int* p = &g_partial[(b << 7) + pair];
        for (int j = 0; j < BPC; ++j) {
            unsigned int w = p[(chunk * BPC + j) * (MAXC * 128)];
            lo += w & 0xFFFFu; hi += w >> 16;
        }
        red[chunk * 256 + 2 * pair]     = lo;
        red[chunk * 256 + 2 * pair + 1] = hi;
        __syncthreads();
        if (t < 256) {
            unsigned int s = red[t] + red[256 + t] + red[512 + t] + red[768 + t];
            sh[t] = s; ss[t] = s;
        }
        __syncthreads();
        for (int off = 1; off < 256; off <<= 1) {
            unsigned int add = (t < 256 && t >= off) ? ss[t - off] : 0u;
            __syncthreads();
            if (t < 256) ss[t] += add;
            __syncthreads();
        }
        unsigned int count = ss[255];
        // replicate JAX/NumPy weak-typed f32 arithmetic (verified exact)
        double eps = (double)(*epsp) / 100.0;
        float fac = (float)(1.0 - eps);
        int k = (int)((float)count * fac);
        int usemax = (count == 0u) || (k >= (int)count);
        if (t == 0) {
            g_usemax[b] = (unsigned)usemax;
            g_ccursor[b] = 0u;
            if (usemax) g_bcount[b] = 0u;
        }
        if (!usemax && t < 256) {
            unsigned int incl = ss[t], excl = incl - sh[t];
            if ((unsigned)k >= excl && (unsigned)k < incl) {
                g_bucket[b] = (unsigned)t;
                g_rem[b]    = k - (int)excl;
                g_bcount[b] = sh[t];
            }
        }
        __syncthreads();
        __threadfence();
        if (t == 0) abump(&g_readyA);
    }

    // --------------------- block 0: class-base exclusive scan (readyB) ----
    if (b == 0) {
        if (t == 0) { while (aload(&g_readyA) < cn) __builtin_amdgcn_s_sleep(2); }
        __syncthreads();
        __threadfence();
        unsigned int v = 0u;
        if (t < MAXC) {
            v = (t < cn && !g_usemax[t]) ? g_bcount[t] : 0u;
            sb1[t] = v;
        }
        __syncthreads();
        for (int off = 1; off < MAXC; off <<= 1) {
            unsigned int add = (t < MAXC && t >= off) ? sb1[t - off] : 0u;
            __syncthreads();
            if (t < MAXC) sb1[t] += add;
            __syncthreads();
        }
        if (t < MAXC) g_cbase[t] = sb1[t] - v;
        __syncthreads();
        __threadfence();
        if (t == 0) abump(&g_readyB);
    } else {
        if (t == 0) { while (aload(&g_readyA) < cn) __builtin_amdgcn_s_sleep(2); }
    }
    __syncthreads();
    __threadfence();

    // ----------------------------------- stage B: gather (all blocks) ----
    if (t < MAXC) {
        int live = (t < cn) && !g_usemax[t];
        sb1[t] = live ? g_bucket[t] : 0xFFFFFFFFu;
        sb2[t] = 0u;
    }
    __syncthreads();

    const int per = ((n + NB2 - 1) / NB2 + 3) & ~3;
    const int i0 = b * per;
    const int i1 = min(n, i0 + per);
    const int nv = (i1 > i0) ? ((i1 - i0) >> 2) : 0;
    const float4* s4 = (const float4*)(score + i0);
    const int4*   l4 = (const int4*)(label + i0);

    // pass A: count matches per class
    for (int j = t; j < nv; j += T2) {
        float4 s = s4[j]; int4 l = l4[j];
        float sv[4] = {s.x, s.y, s.z, s.w};
        int   lv[4] = {l.x, l.y, l.z, l.w};
#pragma unroll
        for (int q = 0; q < 4; ++q) {
            unsigned int u = fkey(sv[q]);
            int c = lv[q] & (MAXC - 1);
            if ((u >> 24) == sb1[c]) atomicAdd(&sb2[c], 1u);
        }
    }
    for (int i = i0 + (nv << 2) + t; i < i1; i += T2) {
        unsigned int u = fkey(score[i]);
        int c = label[i] & (MAXC - 1);
        if ((u >> 24) == sb1[c]) atomicAdd(&sb2[c], 1u);
    }
    __syncthreads();
    if (t == 0) { while (aload(&g_readyB) == 0) __builtin_amdgcn_s_sleep(2); }
    __syncthreads();
    __threadfence();
    if (t < MAXC) {
        unsigned int cnt = sb2[t];
        sb3[t] = cnt ? atomicAdd(&g_ccursor[t], cnt) : 0u;
        sb4[t] = g_cbase[t];
        sb2[t] = 0u;  // reuse as local write cursor
    }
    __syncthreads();
    // pass B: write candidates (slice is cache-hot from pass A)
    for (int j = t; j < nv; j += T2) {
        float4 s = s4[j]; int4 l = l4[j];
        float sv[4] = {s.x, s.y, s.z, s.w};
        int   lv[4] = {l.x, l.y, l.z, l.w};
#pragma unroll
        for (int q = 0; q < 4; ++q) {
            unsigned int u = fkey(sv[q]);
            int c = lv[q] & (MAXC - 1);
            if ((u >> 24) == sb1[c]) {
                unsigned int pos = atomicAdd(&sb2[c], 1u);
                g_cand[sb4[c] + sb3[c] + pos] = u;
            }
        }
    }
    for (int i = i0 + (nv << 2) + t; i < i1; i += T2) {
        unsigned int u = fkey(score[i]);
        int c = label[i] & (MAXC - 1);
        if ((u >> 24) == sb1[c]) {
            unsigned int pos = atomicAdd(&sb2[c], 1u);
            g_cand[sb4[c] + sb3[c] + pos] = u;
        }
    }
    __syncthreads();
    __threadfence();
    if (t == 0) abump(&g_done);

    // ----------------------------- stage C: final select (b < cn only) ----
    if (b >= cn) return;
    if (t == 0) { while (aload(&g_done) < NB2) __builtin_amdgcn_s_sleep(2); }
    __syncthreads();
    __threadfence();

    const int c = b;
    if (g_usemax[c]) {  // empty class / k>=count: global max score
        if (t < NB1) sh[t & 255] = g_blockmax[t];
        __syncthreads();
        for (int off = NB1 / 2; off; off >>= 1) {
            if (t < off) { unsigned int a = sh[t + off]; if (a > sh[t]) sh[t] = a; }
            __syncthreads();
        }
        if (t == 0) out[c] = ikey(sh[0]);
        return;
    }
    const unsigned int base = g_cbase[c];
    const unsigned int m = g_bcount[c];
    int rem = g_rem[c];
    unsigned int pref = g_bucket[c] << 24;
    const unsigned int* src;
    if (m <= STAGE_CAP) {
        for (unsigned int j = t; j < m; j += T2) scand[j] = g_cand[base + j];
        __syncthreads();
        src = scand;
    } else {
        src = &g_cand[base];
        __syncthreads();
    }
    for (int shift = 16; shift >= 0; shift -= 8) {
        if (t < 256) sh[t] = 0u;
        __syncthreads();
        for (unsigned int j = t; j < m; j += T2) {
            unsigned int u = src[j];
            if ((u >> (shift + 8)) == (pref >> (shift + 8)))
                atomicAdd(&sh[(u >> shift) & 255u], 1u);
        }
        __syncthreads();
        if (t < 256) ss[t] = sh[t];
        __syncthreads();
        for (int off = 1; off < 256; off <<= 1) {
            unsigned int add = (t < 256 && t >= off) ? ss[t - off] : 0u;
            __syncthreads();
            if (t < 256) ss[t] += add;
            __syncthreads();
        }
        if (t < 256) {
            unsigned int incl = ss[t], excl = incl - sh[t];
            if ((unsigned)rem >= excl && (unsigned)rem < incl) {
                sel[0] = (unsigned)t; sel[1] = excl;
            }
        }
        __syncthreads();
        rem -= (int)sel[1];
        pref |= sel[0] << shift;
        __syncthreads();
    }
    if (t == 0) out[c] = ikey(pref);
}

extern "C" void kernel_launch(void* const* d_in, const int* in_sizes, int n_in,
                              void* d_out, int out_size, void* d_ws, size_t ws_size,
                              hipStream_t stream) {
    const float* score = (const float*)d_in[0];
    const int*   label = (const int*)d_in[1];
    const int*   cnp   = (const int*)d_in[2];
    const int*   epsp  = (const int*)d_in[3];
    float*       out   = (float*)d_out;
    int n = in_sizes[0];

    scan_kernel<<<NB1, T1, 0, stream>>>(score, label, n, cnp);
    fuse_kernel<<<NB2, T2, 0, stream>>>(score, label, n, cnp, epsp, out);
}

// Round 5
// 41.829 us; speedup vs baseline: 5.8710x; 5.5655x over previous
//
#include <hip/hip_runtime.h>

// Per-class k-th order statistic (quantile) for Logit_Linear.get_th.
// 4-dispatch pipeline (cross-block handoff ONLY at kernel boundaries —
// in-kernel grid sync measured at ~70us/phase on MI355X, rounds 3-4):
//  K1 scan:   64 blocks, LDS-privatized per-class 8-bit histograms (u16x2
//             packed), non-atomic flush to partials + per-block max.
//  K2 select: 1 block/class: reduce partials -> count, k, coarse bucket.
//  K3 gather: 256 blocks, two-pass slice scan, one atomic per (block,class),
//             compact per-class candidate lists.
//  K4 final:  1 block/class: 3x8-bit radix select over staged candidates.

#define MAXC      128        // supports class_num <= 128 (problem: 100)
#define NB1       64         // K1 blocks
#define T1        1024       // K1 threads
#define GG        256        // gather blocks
#define TG        256        // gather threads
#define STAGE_CAP 12288      // candidates staged in LDS in final (48 KB)
#define CAND_CAP  (1u << 21) // candidate buffer words (covers n <= 2M)

__device__ unsigned int g_partial[NB1 * MAXC * 128]; // packed u16 digit pairs
__device__ unsigned int g_blockmax[NB1];
__device__ unsigned int g_bucket[MAXC];
__device__ int          g_rem[MAXC];
__device__ unsigned int g_bcount[MAXC];
__device__ unsigned int g_usemax[MAXC];
__device__ unsigned int g_ccursor[MAXC];
__device__ unsigned int g_cand[CAND_CAP];

__device__ __forceinline__ unsigned int fkey(float f) {
    unsigned int u = __float_as_uint(f);
    return (u & 0x80000000u) ? ~u : (u | 0x80000000u);
}
__device__ __forceinline__ float ikey(unsigned int u) {
    unsigned int b = (u & 0x80000000u) ? (u ^ 0x80000000u) : ~u;
    return __uint_as_float(b);
}

// ------------------------------------------------------------------- K1 ----
__global__ __launch_bounds__(T1) void scan_kernel(const float* __restrict__ score,
                                                  const int* __restrict__ label,
                                                  int n, const int* __restrict__ cnp) {
    __shared__ unsigned int lhist[MAXC * 128];
    __shared__ unsigned int wmax[T1 / 64];
    int cn = *cnp; if (cn > MAXC) cn = MAXC;
    for (int i = threadIdx.x; i < MAXC * 128; i += T1) lhist[i] = 0u;
    __syncthreads();

    const int per = ((n + NB1 - 1) / NB1 + 3) & ~3;
    const int i0 = blockIdx.x * per;
    const int i1 = min(n, i0 + per);
    const int nv = (i1 > i0) ? ((i1 - i0) >> 2) : 0;
    const float4* s4 = (const float4*)(score + i0);
    const int4*   l4 = (const int4*)(label + i0);
    unsigned int lmax = 0u;

    for (int j = threadIdx.x; j < nv; j += T1) {
        float4 s = s4[j]; int4 l = l4[j];
        float sv[4] = {s.x, s.y, s.z, s.w};
        int   lv[4] = {l.x, l.y, l.z, l.w};
#pragma unroll
        for (int q = 0; q < 4; ++q) {
            unsigned int u = fkey(sv[q]);
            int c = lv[q] & (MAXC - 1);
            lmax = lmax > u ? lmax : u;
            atomicAdd(&lhist[(c << 7) | (u >> 25)], ((u >> 24) & 1u) ? 65536u : 1u);
        }
    }
    for (int i = i0 + (nv << 2) + threadIdx.x; i < i1; i += T1) {
        unsigned int u = fkey(score[i]);
        int c = label[i] & (MAXC - 1);
        lmax = lmax > u ? lmax : u;
        atomicAdd(&lhist[(c << 7) | (u >> 25)], ((u >> 24) & 1u) ? 65536u : 1u);
    }
#pragma unroll
    for (int off = 32; off; off >>= 1) {
        unsigned int o = (unsigned int)__shfl_xor((int)lmax, off, 64);
        lmax = lmax > o ? lmax : o;
    }
    if ((threadIdx.x & 63) == 0) wmax[threadIdx.x >> 6] = lmax;
    __syncthreads();
    if (threadIdx.x == 0) {
        unsigned int m = wmax[0];
        for (int w = 1; w < T1 / 64; ++w) m = m > wmax[w] ? m : wmax[w];
        g_blockmax[blockIdx.x] = m;
    }
    unsigned int* dst = &g_partial[blockIdx.x * (MAXC * 128)];
    for (int i = threadIdx.x; i < (cn << 7); i += T1) dst[i] = lhist[i];
}

// ------------------------------------------------------------------- K2 ----
__global__ __launch_bounds__(256) void select0_kernel(const int* __restrict__ cnp,
                                                      const int* __restrict__ epsp) {
    int cn = *cnp; if (cn > MAXC) cn = MAXC;
    int c = blockIdx.x;
    if (c >= cn) return;
    int t = threadIdx.x;
    __shared__ unsigned int red[2 * 256];
    __shared__ unsigned int hist[256];
    __shared__ unsigned int scn[256];

    {   // 2 chunks x 128 pairs; each sums NB1/2 = 32 partial blocks
        const int pair = t & 127, chunk = t >> 7;
        unsigned int lo = 0u, hi = 0u;
        const unsigned int* p = &g_partial[(c << 7) + pair];
        for (int j = 0; j < NB1 / 2; ++j) {
            unsigned int w = p[(chunk * (NB1 / 2) + j) * (MAXC * 128)];
            lo += w & 0xFFFFu; hi += w >> 16;
        }
        red[chunk * 256 + 2 * pair]     = lo;
        red[chunk * 256 + 2 * pair + 1] = hi;
    }
    __syncthreads();
    hist[t] = red[t] + red[256 + t];
    scn[t] = hist[t];
    __syncthreads();
    for (int off = 1; off < 256; off <<= 1) {
        unsigned int add = (t >= off) ? scn[t - off] : 0u;
        __syncthreads();
        scn[t] += add;
        __syncthreads();
    }
    unsigned int count = scn[255];
    // replicate JAX/NumPy weak-typed f32 arithmetic (verified exact, r1-r4)
    double eps = (double)(*epsp) / 100.0;
    float fac = (float)(1.0 - eps);
    int k = (int)((float)count * fac);
    int usemax = (count == 0u) || (k >= (int)count);
    if (t == 0) {
        g_usemax[c] = (unsigned)usemax;
        g_ccursor[c] = 0u;
        if (usemax) g_bcount[c] = 0u;
    }
    if (!usemax) {
        unsigned int incl = scn[t], excl = incl - hist[t];
        if ((unsigned)k >= excl && (unsigned)k < incl) {
            g_bucket[c] = (unsigned)t;
            g_rem[c]    = k - (int)excl;
            g_bcount[c] = hist[t];
        }
    }
}

// ------------------------------------------------------------------- K3 ----
__global__ __launch_bounds__(TG) void gather_kernel(const float* __restrict__ score,
                                                    const int* __restrict__ label,
                                                    int n, const int* __restrict__ cnp) {
    int cn = *cnp; if (cn > MAXC) cn = MAXC;
    int t = threadIdx.x;
    __shared__ unsigned int sbucket[MAXC];
    __shared__ unsigned int scnt[MAXC];
    __shared__ unsigned int sbase[MAXC];
    __shared__ unsigned int scbase[MAXC];
    for (int c = t; c < cn; c += TG) {
        unsigned int um = g_usemax[c];
        sbucket[c] = um ? 0xFFFFFFFFu : g_bucket[c];
        scnt[c] = 0u;
        scbase[c] = um ? 0u : g_bcount[c];   // temp: per-class totals
    }
    __syncthreads();
    if (t == 0) {  // exclusive prefix over class totals -> global class bases
        unsigned int cb = 0u;
        for (int c = 0; c < cn; ++c) { unsigned int v = scbase[c]; scbase[c] = cb; cb += v; }
    }
    __syncthreads();

    const int per = ((n + GG - 1) / GG + 3) & ~3;
    const int i0 = blockIdx.x * per;
    const int i1 = min(n, i0 + per);
    const int nv = (i1 > i0) ? ((i1 - i0) >> 2) : 0;
    const float4* s4 = (const float4*)(score + i0);
    const int4*   l4 = (const int4*)(label + i0);

    // pass A: count matches per class
    for (int j = t; j < nv; j += TG) {
        float4 s = s4[j]; int4 l = l4[j];
        float sv[4] = {s.x, s.y, s.z, s.w};
        int   lv[4] = {l.x, l.y, l.z, l.w};
#pragma unroll
        for (int q = 0; q < 4; ++q) {
            unsigned int u = fkey(sv[q]);
            int c = lv[q] & (MAXC - 1);
            if ((u >> 24) == sbucket[c]) atomicAdd(&scnt[c], 1u);
        }
    }
    for (int i = i0 + (nv << 2) + t; i < i1; i += TG) {
        unsigned int u = fkey(score[i]);
        int c = label[i] & (MAXC - 1);
        if ((u >> 24) == sbucket[c]) atomicAdd(&scnt[c], 1u);
    }
    __syncthreads();
    for (int c = t; c < cn; c += TG) {
        unsigned int cnt = scnt[c];
        sbase[c] = cnt ? atomicAdd(&g_ccursor[c], cnt) : 0u;
        scnt[c] = 0u;   // reuse as local write cursor
    }
    __syncthreads();
    // pass B: write candidates (slice is L1/L2-hot from pass A)
    for (int j = t; j < nv; j += TG) {
        float4 s = s4[j]; int4 l = l4[j];
        float sv[4] = {s.x, s.y, s.z, s.w};
        int   lv[4] = {l.x, l.y, l.z, l.w};
#pragma unroll
        for (int q = 0; q < 4; ++q) {
            unsigned int u = fkey(sv[q]);
            int c = lv[q] & (MAXC - 1);
            if ((u >> 24) == sbucket[c]) {
                unsigned int pos = atomicAdd(&scnt[c], 1u);
                g_cand[scbase[c] + sbase[c] + pos] = u;
            }
        }
    }
    for (int i = i0 + (nv << 2) + t; i < i1; i += TG) {
        unsigned int u = fkey(score[i]);
        int c = label[i] & (MAXC - 1);
        if ((u >> 24) == sbucket[c]) {
            unsigned int pos = atomicAdd(&scnt[c], 1u);
            g_cand[scbase[c] + sbase[c] + pos] = u;
        }
    }
}

// ------------------------------------------------------------------- K4 ----
__global__ __launch_bounds__(256) void final_kernel(const int* __restrict__ cnp,
                                                    float* __restrict__ out) {
    int cn = *cnp; if (cn > MAXC) cn = MAXC;
    int c = blockIdx.x;
    if (c >= cn) return;
    int t = threadIdx.x;
    __shared__ unsigned int sh[256];
    __shared__ unsigned int ss[256];
    __shared__ unsigned int sel[2];
    __shared__ unsigned int scb[MAXC];
    __shared__ unsigned int scand[STAGE_CAP];

    if (g_usemax[c]) {  // empty class (or k>=count): global max score
        sh[t] = (t < NB1) ? g_blockmax[t] : 0u;
        __syncthreads();
        for (int off = 32; off; off >>= 1) {
            if (t < off && t + off < NB1) { unsigned int a = sh[t + off]; if (a > sh[t]) sh[t] = a; }
            __syncthreads();
        }
        if (t == 0) out[c] = ikey(sh[0]);
        return;
    }

    for (int cc = t; cc < cn; cc += 256) scb[cc] = g_usemax[cc] ? 0u : g_bcount[cc];
    __syncthreads();
    if (t == 0) {
        unsigned int cb = 0u;
        for (int cc = 0; cc < cn; ++cc) { unsigned int v = scb[cc]; scb[cc] = cb; cb += v; }
    }
    __syncthreads();

    const unsigned int base = scb[c], m = g_bcount[c], bucket = g_bucket[c];
    int rem = g_rem[c];
    const unsigned int* src;
    if (m <= STAGE_CAP) {
        for (unsigned int j = t; j < m; j += 256) scand[j] = g_cand[base + j];
        __syncthreads();
        src = scand;
    } else {
        src = &g_cand[base];
    }

    unsigned int pref = bucket << 24;
    for (int shift = 16; shift >= 0; shift -= 8) {
        sh[t] = 0u; __syncthreads();
        for (unsigned int j = t; j < m; j += 256) {
            unsigned int u = src[j];
            if ((u >> (shift + 8)) == (pref >> (shift + 8)))
                atomicAdd(&sh[(u >> shift) & 255u], 1u);
        }
        __syncthreads();
        ss[t] = sh[t]; __syncthreads();
        for (int off = 1; off < 256; off <<= 1) {
            unsigned int add = (t >= off) ? ss[t - off] : 0u;
            __syncthreads();
            ss[t] += add;
            __syncthreads();
        }
        unsigned int incl = ss[t], excl = incl - sh[t];
        if ((unsigned)rem >= excl && (unsigned)rem < incl) { sel[0] = (unsigned)t; sel[1] = excl; }
        __syncthreads();
        rem -= (int)sel[1];
        pref |= sel[0] << shift;
        __syncthreads();
    }
    if (t == 0) out[c] = ikey(pref);
}

extern "C" void kernel_launch(void* const* d_in, const int* in_sizes, int n_in,
                              void* d_out, int out_size, void* d_ws, size_t ws_size,
                              hipStream_t stream) {
    const float* score = (const float*)d_in[0];
    const int*   label = (const int*)d_in[1];
    const int*   cnp   = (const int*)d_in[2];
    const int*   epsp  = (const int*)d_in[3];
    float*       out   = (float*)d_out;
    int n = in_sizes[0];

    scan_kernel   <<<NB1,  T1,  0, stream>>>(score, label, n, cnp);
    select0_kernel<<<MAXC, 256, 0, stream>>>(cnp, epsp);
    gather_kernel <<<GG,   TG,  0, stream>>>(score, label, n, cnp);
    final_kernel  <<<MAXC, 256, 0, stream>>>(cnp, out);
}